// Round 18
// baseline (343.246 us; speedup 1.0000x reference)
//
#include <hip/hip_runtime.h>
#include <math.h>

// ECMNet on gfx950 — R17 + prep register-prefetch pipeline (4 rows/block),
// pinned S_post=4. B=2, F=2048, T=750, C=20, topK=93
namespace {
constexpr int kF = 2048;
constexpr int kT = 750;
constexpr int kC = 20;
constexpr int kTop = 93;
}

typedef __bf16 bf16x8 __attribute__((ext_vector_type(8)));
typedef float f32x4 __attribute__((ext_vector_type(4)));

__device__ __forceinline__ ushort f2bf(float f) {
  uint u = __builtin_bit_cast(uint, f);
  uint r = u + 0x7FFFu + ((u >> 16) & 1u);
  return (ushort)(r >> 16);
}
__device__ __forceinline__ float bf2f(ushort u) {
  return __builtin_bit_cast(float, ((uint)u) << 16);
}
__device__ __forceinline__ float leaky(float v) { return v > 0.f ? v : 0.01f * v; }

__device__ __forceinline__ void gload_lds16(const ushort* g, ushort* l) {
  __builtin_amdgcn_global_load_lds(
      (const __attribute__((address_space(1))) void*)g,
      (__attribute__((address_space(3))) void*)l, 16, 0, 0);
}

// ---------------------------------------------------------------------------
// prep_all (R18): one launch for all preprocessing.
//  blk 0..511     : w1 rows 4/blk -> Wt1 (reg-prefetch pipelined)
//  blk 512..1023  : w2 rows 4/blk -> Wt2
//  blk 1024..1791 : x transpose -> xTt
//  blk 1792..5887 : xJ build
//  extras: wc convert (blk<160), zpage (blk 0), compact list (blk 512)
// cnt: [0]=NS, [1]=NS*3, [2]=1500, [4+b]=boff_b, [6+b]=nb_b. meta=(b,c,a,isfg)
// ---------------------------------------------------------------------------
__global__ __launch_bounds__(256) void prep_all_kernel(
    const float* __restrict__ w1, const float* __restrict__ w2,
    const float* __restrict__ wc, const float* __restrict__ x,
    const int* __restrict__ lbl,
    ushort* __restrict__ Wt1, ushort* __restrict__ Wt2,
    ushort* __restrict__ wcb, ushort* __restrict__ zpage,
    ushort* __restrict__ xTt, ushort* __restrict__ xJ,
    int4* __restrict__ meta, int* __restrict__ cnt) {
  __shared__ float smem[6144];   // 24 KB
  const int blk = blockIdx.x;
  const int tid = threadIdx.x;

  if (blk < 1024) {
    // ---- weight conversion: 4 rows per block, reg-prefetch pipeline ----
    const float* w = (blk < 512) ? w1 : w2;
    ushort* Wt = (blk < 512) ? Wt1 : Wt2;
    const int base = (blk & 511) * 4;
    float4 pre[6];
    {
      const float4* src = (const float4*)(w + (size_t)base * 6144);
#pragma unroll
      for (int i = 0; i < 6; ++i)
        ((float4*)smem)[tid + i * 256] = src[tid + i * 256];
    }
    for (int r = 0; r < 4; ++r) {
      if (r + 1 < 4) {     // issue next row loads early (overlap with convert)
        const float4* srcn = (const float4*)(w + (size_t)(base + r + 1) * 6144);
#pragma unroll
        for (int i = 0; i < 6; ++i) pre[i] = srcn[tid + i * 256];
      }
      __syncthreads();     // row r fully in smem
      float rv[24];
      const float4* lp = (const float4*)smem + tid * 6;
#pragma unroll
      for (int k = 0; k < 6; ++k) {
        float4 f = lp[k];
        rv[k * 4 + 0] = f.x; rv[k * 4 + 1] = f.y;
        rv[k * 4 + 2] = f.z; rv[k * 4 + 3] = f.w;
      }
      const int co = base + r;
      const int ci0 = tid * 8;
#pragma unroll
      for (int tap = 0; tap < 3; ++tap) {
        uint4 pk;
        pk.x = (uint)f2bf(rv[0 * 3 + tap]) | ((uint)f2bf(rv[1 * 3 + tap]) << 16);
        pk.y = (uint)f2bf(rv[2 * 3 + tap]) | ((uint)f2bf(rv[3 * 3 + tap]) << 16);
        pk.z = (uint)f2bf(rv[4 * 3 + tap]) | ((uint)f2bf(rv[5 * 3 + tap]) << 16);
        pk.w = (uint)f2bf(rv[6 * 3 + tap]) | ((uint)f2bf(rv[7 * 3 + tap]) << 16);
        *(uint4*)(Wt + (size_t)tap * kF * kF + (size_t)co * kF + ci0) = pk;
      }
      __syncthreads();     // all lanes done reading smem
      if (r + 1 < 4) {
#pragma unroll
        for (int i = 0; i < 6; ++i)
          ((float4*)smem)[tid + i * 256] = pre[i];
      }
    }
    if (blk < 160) {                      // wc: 40960 elems
      int i = blk * 256 + tid;
      wcb[i] = f2bf(wc[i]);
    }
    if (blk == 0) {
      ((float4*)zpage)[tid] = (float4){0.f, 0.f, 0.f, 0.f};
    }
    if (blk == 512 && tid == 0) {         // compact list
      int n = 0;
      for (int b2 = 0; b2 < 2; ++b2) {
        cnt[4 + b2] = n;
        for (int c = 0; c < kC; ++c) { meta[n] = make_int4(b2, c, c, 1); ++n; }
        for (int c = 0; c < kC; ++c)
          for (int a2 = 0; a2 < kC; ++a2)
            if (lbl[b2 * kC + c] > 0 || c == a2) { meta[n] = make_int4(b2, c, a2, 0); ++n; }
        cnt[6 + b2] = (n - cnt[4 + b2]);
      }
      cnt[0] = n; cnt[1] = n * 3; cnt[2] = 1500; cnt[3] = 0;
    }
  } else if (blk < 1792) {
    // ---- transpose tile: smem as [64][65] ----
    const int loc = blk - 1024;
    const int b = loc / 384, r = loc % 384;
    const int by = r / 12, bx = r % 12;
    const int t0 = bx * 64, f0 = by * 64;
    const int tx = tid & 63, ty4 = tid >> 6;
#pragma unroll
    for (int i = 0; i < 16; ++i) {
      int lf = ty4 + i * 4;
      int t = t0 + tx;
      smem[lf * 65 + tx] = (t < kT) ? x[((size_t)b * kF + f0 + lf) * kT + t] : 0.f;
    }
    __syncthreads();
#pragma unroll
    for (int i = 0; i < 16; ++i) {
      int lt = ty4 + i * 4;
      int t = t0 + lt;
      if (t < kT)
        xTt[(size_t)(b * kT + t) * kF + f0 + tx] = f2bf(smem[tx * 65 + lt]);
    }
  } else {
    // ---- xJ build ----
    const int bid = blk - 1792;           // 0..4095
    const int b = bid >> 11, f = bid & 2047;
    const float* xr = x + ((size_t)b * kF + f) * kT;
    for (int t = tid; t < kT; t += 256) smem[t] = xr[t];
    __syncthreads();
    const int j = tid;
#pragma unroll
    for (int g = 0; g < 3; ++g) {
      float v = (j < 250) ? smem[j * 3 + g] : 0.f;
      xJ[(((size_t)(b * 3 + g) * kF + f) << 8) + j] = f2bf(v);
    }
  }
}

// ---------------------------------------------------------------------------
// W2c[bg][r][j] bf16 from compact meta
// ---------------------------------------------------------------------------
__global__ __launch_bounds__(256) void ww_build_kernel(
    const float* __restrict__ wab, const int4* __restrict__ meta,
    const int* __restrict__ cnt, ushort* __restrict__ W2) {
  const int bg = blockIdx.x;
  const int b = bg / 3, g = bg % 3;
  const int r0 = blockIdx.y * 32;
  const int nb = cnt[6 + b], boff = cnt[4 + b];
  if (r0 >= nb) return;
  __shared__ float ws[kC][256];
  for (int i = threadIdx.x; i < kC * 250; i += 256) {
    int c = i / 250, j = i % 250;
    ws[c][j] = wab[(size_t)(b * kC + c) * kT + j * 3 + g];
  }
  __syncthreads();
  ushort* Wb = W2 + (size_t)bg * 512 * 256;
  const int j = threadIdx.x;
  for (int rr = 0; rr < 32; ++rr) {
    int r = r0 + rr;
    if (r >= nb) break;
    int4 m = meta[boff + r];
    float v = 0.f;
    if (j < 250)
      v = m.w ? ws[m.y][j] : ws[m.z][j] * (1.f - ws[m.y][j]);
    Wb[(size_t)r * 256 + j] = f2bf(v);
  }
}

// ---------------------------------------------------------------------------
// ww GEMM (128x128, 2-phase)
// ---------------------------------------------------------------------------
__global__ __launch_bounds__(256) void ww_gemm_kernel(
    const ushort* __restrict__ xJ, const ushort* __restrict__ W2,
    const int* __restrict__ cnt, ushort* __restrict__ FeatY) {
  const int bg = blockIdx.z;
  const int b = bg / 3, g = bg % 3;
  const int nb = cnt[6 + b], boff = cnt[4 + b];
  const int s0 = blockIdx.x * 128;
  if (s0 >= nb) return;
  __shared__ ushort sA[2][128 * 64];
  __shared__ ushort sB[2][128 * 64];
  const int tid = threadIdx.x;
  const int w = tid >> 6, lane = tid & 63;
  const int wm = w >> 1, wn = w & 1;
  const int f0 = blockIdx.y * 128;
  const ushort* A = xJ + ((size_t)bg * kF << 8);
  const ushort* Bp = W2 + (size_t)bg * 512 * 256;
  const int srow = lane >> 3;
  const int selem = ((lane & 7) ^ srow) * 8;
  f32x4 acc[4][4];
#pragma unroll
  for (int i = 0; i < 4; ++i)
#pragma unroll
    for (int j = 0; j < 4; ++j) acc[i][j] = (f32x4){0.f, 0.f, 0.f, 0.f};

  auto STAGE = [&](int buf, int kt) {
    const int kin = kt * 64;
#pragma unroll
    for (int i = 0; i < 4; ++i) {
      int r = (w * 4 + i) * 8 + srow;
      gload_lds16(A + (size_t)(f0 + r) * 256 + kin + selem,
                  &sA[buf][(w * 4 + i) * 512]);
    }
#pragma unroll
    for (int i = 0; i < 4; ++i) {
      int r = (w * 4 + i) * 8 + srow;
      gload_lds16(Bp + (size_t)(s0 + r) * 256 + kin + selem,
                  &sB[buf][(w * 4 + i) * 512]);
    }
  };

  STAGE(0, 0);
  asm volatile("s_waitcnt vmcnt(0)" ::: "memory");
  __builtin_amdgcn_s_barrier();

  int cur = 0;
  for (int kt = 0; kt < 4; ++kt) {
    if (kt + 1 < 4) STAGE(cur ^ 1, kt + 1);
#pragma unroll
    for (int ksub = 0; ksub < 2; ++ksub) {
      bf16x8 af[4], bfv[4];
      const int rlow = lane & 7;
#pragma unroll
      for (int fm = 0; fm < 4; ++fm) {
        int row = wm * 64 + fm * 16 + (lane & 15);
        int c16 = (ksub * 4 + (lane >> 4)) ^ rlow;
        af[fm] = *(const bf16x8*)&sA[cur][row * 64 + c16 * 8];
      }
#pragma unroll
      for (int fn = 0; fn < 4; ++fn) {
        int row = wn * 64 + fn * 16 + (lane & 15);
        int c16 = (ksub * 4 + (lane >> 4)) ^ rlow;
        bfv[fn] = *(const bf16x8*)&sB[cur][row * 64 + c16 * 8];
      }
#pragma unroll
      for (int fm = 0; fm < 4; ++fm)
#pragma unroll
        for (int fn = 0; fn < 4; ++fn)
          acc[fm][fn] = __builtin_amdgcn_mfma_f32_16x16x32_bf16(
              af[fm], bfv[fn], acc[fm][fn], 0, 0, 0);
    }
    asm volatile("s_waitcnt vmcnt(0)" ::: "memory");
    __builtin_amdgcn_s_barrier();
    cur ^= 1;
  }

#pragma unroll
  for (int fm = 0; fm < 4; ++fm) {
#pragma unroll
    for (int fn = 0; fn < 4; ++fn) {
      int s = s0 + wn * 64 + fn * 16 + (lane & 15);
      if (s >= nb) continue;
      int row = f0 + wm * 64 + fm * 16 + ((lane >> 4) << 2);
      ushort4 o;
      o.x = f2bf(acc[fm][fn][0]);
      o.y = f2bf(acc[fm][fn][1]);
      o.z = f2bf(acc[fm][fn][2]);
      o.w = f2bf(acc[fm][fn][3]);
      *(ushort4*)&FeatY[(size_t)((boff + s) * 3 + g) * kF + row] = o;
    }
  }
}

// ---------------------------------------------------------------------------
// Direct-conv GEMM (R13 exact)
// ---------------------------------------------------------------------------
template <int L>
__global__ __launch_bounds__(512, 1) void gemm_conv_kernel(
    const ushort* __restrict__ A, const ushort* __restrict__ B,
    const ushort* __restrict__ zpage, ushort* __restrict__ Cpart,
    const int* __restrict__ ncp, int NP, int ktn_base, int ktrem) {
  extern __shared__ ushort lds[];
  const int nc = *ncp;
  const int tid = threadIdx.x;
  const int wid = tid >> 6, lane = tid & 63;
  const int wr = wid >> 2, wc = wid & 3;
  const int gx = gridDim.x, gy = gridDim.y;
  const int nwg = gx * gy * gridDim.z;
  const int h = blockIdx.x + gx * (blockIdx.y + gy * blockIdx.z);
  const int lgc = (h & 7) * (nwg >> 3) + (h >> 3);
  const int bx = lgc % gx;
  const int byz = lgc / gx;
  const int co0 = (byz % gy) * 256;
  const int col0 = bx * 256;
  if (col0 >= nc) return;
  const int z = byz / gy;
  const int kt0 = z * ktn_base + (z < ktrem ? z : ktrem);
  const int ktn = ktn_base + (z < ktrem ? 1 : 0);
  const int ktend = kt0 + ktn;

  const int pofs = lane >> 3;
  const int lin_s = (lane & 7) ^ pofs;
  const int mofs = 2 * pofs + (lin_s >> 2);
  const int qseg = (lin_s & 3) * 8;
  const int l15 = lane & 15;
  const int seg8 = ((((l15 & 1) << 2) + (lane >> 4)) ^ (l15 >> 1)) * 8;
  const int off_rl = (l15 >> 1) * 64 + seg8;

  f32x4 acc[8][4];
#pragma unroll
  for (int i = 0; i < 8; ++i)
#pragma unroll
    for (int j = 0; j < 4; ++j) acc[i][j] = (f32x4){0.f, 0.f, 0.f, 0.f};

  auto STAGE_A = [&](int buf, int kt) {
    const int tap = kt >> 6;
    const int kin = (kt & 63) * 32;
    const size_t abase = (size_t)tap * kF * kF + kin + qseg;
#pragma unroll
    for (int l = 0; l < 2; ++l) {
      int m = l * 128 + wid * 16 + mofs;
      gload_lds16(A + abase + (size_t)(co0 + m) * kF,
                  &lds[buf * 16384 + l * 4096 + wid * 512]);
    }
  };
  auto STAGE_B = [&](int buf, int kt) {
    const int tap = kt >> 6;
    const int kin = (kt & 63) * 32;
#pragma unroll
    for (int l = 0; l < 2; ++l) {
      int m = l * 128 + wid * 16 + mofs;
      int col = col0 + m;
      int t = col - (col / L) * L;
      int tt = t + tap - 1;
      const ushort* src = (col < nc && tt >= 0 && tt < L)
          ? B + (size_t)(col + tap - 1) * kF + kin + qseg
          : zpage + qseg;
      gload_lds16(src, &lds[buf * 16384 + 8192 + l * 4096 + wid * 512]);
    }
  };

  STAGE_A(kt0 & 3, kt0);           STAGE_B(kt0 & 3, kt0);
  STAGE_A((kt0 + 1) & 3, kt0 + 1); STAGE_B((kt0 + 1) & 3, kt0 + 1);
  STAGE_A((kt0 + 2) & 3, kt0 + 2); STAGE_B((kt0 + 2) & 3, kt0 + 2);
  asm volatile("s_waitcnt vmcnt(8)" ::: "memory");
  __builtin_amdgcn_s_barrier();
  __builtin_amdgcn_sched_barrier(0);

  for (int kt = kt0; kt < ktend; ++kt) {
    const int buf = kt & 3;
    const int ts = (kt + 3 < ktend) ? kt + 3 : ktend - 1;
    const int bufs = ts & 3;
    const ushort* bb = &lds[buf * 16384];
    bf16x8 bfv[4], af[4];
    STAGE_A(bufs, ts);
#pragma unroll
    for (int fn = 0; fn < 4; ++fn)
      bfv[fn] = *(const bf16x8*)&bb[8192 + wc * 2048 + fn * 512 + off_rl];
#pragma unroll
    for (int fm = 0; fm < 4; ++fm)
      af[fm] = *(const bf16x8*)&bb[wr * 4096 + fm * 512 + off_rl];
    asm volatile("s_waitcnt lgkmcnt(0)" ::: "memory");
    __builtin_amdgcn_sched_barrier(0);
    __builtin_amdgcn_s_setprio(1);
#pragma unroll
    for (int fm = 0; fm < 4; ++fm)
#pragma unroll
      for (int fn = 0; fn < 4; ++fn)
        acc[fm][fn] = __builtin_amdgcn_mfma_f32_16x16x32_bf16(
            af[fm], bfv[fn], acc[fm][fn], 0, 0, 0);
    __builtin_amdgcn_s_setprio(0);
    STAGE_B(bufs, ts);
#pragma unroll
    for (int fm = 0; fm < 4; ++fm)
      af[fm] = *(const bf16x8*)&bb[wr * 4096 + (fm + 4) * 512 + off_rl];
    asm volatile("s_waitcnt lgkmcnt(0)" ::: "memory");
    __builtin_amdgcn_sched_barrier(0);
    __builtin_amdgcn_s_setprio(1);
#pragma unroll
    for (int fm = 0; fm < 4; ++fm)
#pragma unroll
      for (int fn = 0; fn < 4; ++fn)
        acc[fm + 4][fn] = __builtin_amdgcn_mfma_f32_16x16x32_bf16(
            af[fm], bfv[fn], acc[fm + 4][fn], 0, 0, 0);
    __builtin_amdgcn_s_setprio(0);
    asm volatile("s_waitcnt vmcnt(8)" ::: "memory");
    __builtin_amdgcn_s_barrier();
    __builtin_amdgcn_sched_barrier(0);
  }

  ushort* Cz = Cpart + (size_t)z * NP * kF;
#pragma unroll
  for (int fm = 0; fm < 8; ++fm) {
#pragma unroll
    for (int fn = 0; fn < 4; ++fn) {
      int col = col0 + wc * 64 + fn * 16 + l15;
      int row = co0 + wr * 128 + fm * 16 + ((lane >> 4) << 2);
      ushort4 o;
      o.x = f2bf(acc[fm][fn][0]);
      o.y = f2bf(acc[fm][fn][1]);
      o.z = f2bf(acc[fm][fn][2]);
      o.w = f2bf(acc[fm][fn][3]);
      *(ushort4*)&Cz[(size_t)col * kF + row] = o;
    }
  }
}

// ---------------------------------------------------------------------------
// reduce bf16 partials over S + bias + leaky -> bf16 [col][2048]
// ---------------------------------------------------------------------------
__global__ __launch_bounds__(256) void reduce_kernel(
    const ushort* __restrict__ Cpart, const float* __restrict__ bias,
    ushort* __restrict__ Y, const int* __restrict__ ncp, int NP, int S) {
  const int col = blockIdx.x;
  if (col >= *ncp) return;
  const int row0 = threadIdx.x * 8;
  float s[8] = {};
  for (int z = 0; z < S; ++z) {
    const ushort* p = &Cpart[((size_t)z * NP + col) * kF + row0];
    ushort4 a = *(const ushort4*)p;
    ushort4 b = *(const ushort4*)(p + 4);
    s[0] += bf2f(a.x); s[1] += bf2f(a.y); s[2] += bf2f(a.z); s[3] += bf2f(a.w);
    s[4] += bf2f(b.x); s[5] += bf2f(b.y); s[6] += bf2f(b.z); s[7] += bf2f(b.w);
  }
  float4 bv0 = *(const float4*)&bias[row0];
  float4 bv1 = *(const float4*)&bias[row0 + 4];
  ushort4 o0, o1;
  o0.x = f2bf(leaky(s[0] + bv0.x)); o0.y = f2bf(leaky(s[1] + bv0.y));
  o0.z = f2bf(leaky(s[2] + bv0.z)); o0.w = f2bf(leaky(s[3] + bv0.w));
  o1.x = f2bf(leaky(s[4] + bv1.x)); o1.y = f2bf(leaky(s[5] + bv1.y));
  o1.z = f2bf(leaky(s[6] + bv1.z)); o1.w = f2bf(leaky(s[7] + bv1.w));
  *(ushort4*)&Y[(size_t)col * kF + row0] = o0;
  *(ushort4*)&Y[(size_t)col * kF + row0 + 4] = o1;
}

// ---------------------------------------------------------------------------
// fused main-conv2 reduce + seqcas + wa (h2 never materialized)
// ---------------------------------------------------------------------------
__global__ __launch_bounds__(256) void reduce_seqcas_kernel(
    const ushort* __restrict__ Cpart, const float* __restrict__ bias,
    const ushort* __restrict__ wcb, const float* __restrict__ watt,
    const float* __restrict__ batt, float* __restrict__ seq,
    float* __restrict__ wa, int NP, int S) {
  __shared__ float red[4][kC];
  __shared__ float sseq[kC];
  const int col = blockIdx.x;          // b*750+t
  const int tid = threadIdx.x;
  const int wid = tid >> 6, lane = tid & 63;
  const int row0 = tid * 8;
  float s[8] = {};
  for (int z = 0; z < S; ++z) {
    const ushort* p = &Cpart[((size_t)z * NP + col) * kF + row0];
    ushort4 a4 = *(const ushort4*)p;
    ushort4 b4 = *(const ushort4*)(p + 4);
    s[0] += bf2f(a4.x); s[1] += bf2f(a4.y); s[2] += bf2f(a4.z); s[3] += bf2f(a4.w);
    s[4] += bf2f(b4.x); s[5] += bf2f(b4.y); s[6] += bf2f(b4.z); s[7] += bf2f(b4.w);
  }
  float4 bv0 = *(const float4*)&bias[row0];
  float4 bv1 = *(const float4*)&bias[row0 + 4];
  float a[8];
  a[0] = leaky(s[0] + bv0.x); a[1] = leaky(s[1] + bv0.y);
  a[2] = leaky(s[2] + bv0.z); a[3] = leaky(s[3] + bv0.w);
  a[4] = leaky(s[4] + bv1.x); a[5] = leaky(s[5] + bv1.y);
  a[6] = leaky(s[6] + bv1.z); a[7] = leaky(s[7] + bv1.w);
  float p[kC];
#pragma unroll
  for (int c = 0; c < kC; ++c) {
    const ushort* wr = wcb + (size_t)c * kF + row0;
    ushort4 wa4 = *(const ushort4*)wr;
    ushort4 wb4 = *(const ushort4*)(wr + 4);
    p[c] = bf2f(wa4.x) * a[0] + bf2f(wa4.y) * a[1] +
           bf2f(wa4.z) * a[2] + bf2f(wa4.w) * a[3] +
           bf2f(wb4.x) * a[4] + bf2f(wb4.y) * a[5] +
           bf2f(wb4.z) * a[6] + bf2f(wb4.w) * a[7];
  }
#pragma unroll
  for (int off = 32; off; off >>= 1)
#pragma unroll
    for (int c = 0; c < kC; ++c) p[c] += __shfl_xor(p[c], off);
  if (lane == 0)
#pragma unroll
    for (int c = 0; c < kC; ++c) red[wid][c] = p[c];
  __syncthreads();
  if (tid < kC)
    sseq[tid] = red[0][tid] + red[1][tid] + red[2][tid] + red[3][tid];
  __syncthreads();
  if (tid < kC) {
    float z = batt[tid];
#pragma unroll
    for (int a2 = 0; a2 < kC; ++a2) z += watt[tid * kC + a2] * sseq[a2];
    const int b = col / kT, t = col - b * kT;
    seq[(size_t)(b * kC + tid) * kT + t] = sseq[tid];
    wa[(size_t)(b * kC + tid) * kT + t] = 1.f / (1.f + expf(-z));
  }
}

// ---------------------------------------------------------------------------
// fused post-conv2 reduce + classifier dot
// ---------------------------------------------------------------------------
__global__ __launch_bounds__(256) void reduce_cls_kernel(
    const ushort* __restrict__ Cpart, const float* __restrict__ bias,
    const float* __restrict__ wc, const int4* __restrict__ meta,
    const int* __restrict__ cnt, float* __restrict__ scpart, int NP, int S) {
  __shared__ float red[256];
  const int col = blockIdx.x;
  if (col >= cnt[1]) return;
  const int4 m = meta[col / 3];
  const int cls = m.w ? m.y : m.z;
  const int row0 = threadIdx.x * 8;
  float s[8] = {};
  for (int z = 0; z < S; ++z) {
    const ushort* p = &Cpart[((size_t)z * NP + col) * kF + row0];
    ushort4 a = *(const ushort4*)p;
    ushort4 b = *(const ushort4*)(p + 4);
    s[0] += bf2f(a.x); s[1] += bf2f(a.y); s[2] += bf2f(a.z); s[3] += bf2f(a.w);
    s[4] += bf2f(b.x); s[5] += bf2f(b.y); s[6] += bf2f(b.z); s[7] += bf2f(b.w);
  }
  float4 bv0 = *(const float4*)&bias[row0];
  float4 bv1 = *(const float4*)&bias[row0 + 4];
  float4 w0 = *(const float4*)&wc[(size_t)cls * kF + row0];
  float4 w1 = *(const float4*)&wc[(size_t)cls * kF + row0 + 4];
  float acc =
      bf2f(f2bf(leaky(s[0] + bv0.x))) * w0.x + bf2f(f2bf(leaky(s[1] + bv0.y))) * w0.y +
      bf2f(f2bf(leaky(s[2] + bv0.z))) * w0.z + bf2f(f2bf(leaky(s[3] + bv0.w))) * w0.w +
      bf2f(f2bf(leaky(s[4] + bv1.x))) * w1.x + bf2f(f2bf(leaky(s[5] + bv1.y))) * w1.y +
      bf2f(f2bf(leaky(s[6] + bv1.z))) * w1.z + bf2f(f2bf(leaky(s[7] + bv1.w))) * w1.w;
  red[threadIdx.x] = acc;
  __syncthreads();
  for (int t = 128; t > 0; t >>= 1) {
    if (threadIdx.x < t) red[threadIdx.x] += red[threadIdx.x + t];
    __syncthreads();
  }
  if (threadIdx.x == 0) scpart[col] = red[0];
}

// gather per-sample mean over g and scatter (deterministic)
__global__ __launch_bounds__(256) void cls2_kernel(
    const float* __restrict__ scpart, const int4* __restrict__ meta,
    const int* __restrict__ cnt, float* __restrict__ out40,
    float* __restrict__ scb) {
  const int n = blockIdx.x * 256 + threadIdx.x;
  if (n >= cnt[0]) return;
  const int4 m = meta[n];
  float v = (scpart[3 * n] + scpart[3 * n + 1] + scpart[3 * n + 2]) * (1.f / 3.f);
  if (m.w) out40[m.x * kC + m.y] = v;
  else scb[m.x * 400 + m.y * kC + m.z] = v;
}

// top-93 mean over T per (b,c) row — one wave per row, barrier-free
__global__ __launch_bounds__(64) void score_pre_kernel(
    const float* __restrict__ seq, float* __restrict__ out) {
  const int n = blockIdx.x;
  const int lane = threadIdx.x;
  float v[12];
#pragma unroll
  for (int i = 0; i < 12; ++i) {
    int idx = lane + i * 64;
    v[i] = (idx < kT) ? seq[(size_t)n * kT + idx] : -1e30f;
  }
  float sum = 0.f;
  for (int it = 0; it < kTop; ++it) {
    float lm = v[0];
#pragma unroll
    for (int i = 1; i < 12; ++i) lm = fmaxf(lm, v[i]);
    float wm = lm;
#pragma unroll
    for (int off = 32; off; off >>= 1) wm = fmaxf(wm, __shfl_xor(wm, off));
    sum += wm;
    unsigned long long ball = __ballot(lm == wm);
    int first = __ffsll(ball) - 1;
    bool own = (lane == first);
    bool done = false;
#pragma unroll
    for (int i = 0; i < 12; ++i) {
      bool hit = own && !done && (v[i] == wm);
      if (hit) { v[i] = -1e30f; done = true; }
    }
  }
  if (lane == 0) out[n] = sum / (float)kTop;
}

// collect + concat + softmax
__global__ void final_kernel(const float* __restrict__ score_post,
                             const float* __restrict__ sc_buf,
                             const int* __restrict__ label,
                             float* __restrict__ out) {
  __shared__ float z[2 * kC];
  __shared__ float collect[kC];
  const int b = blockIdx.x;
  const int tid = threadIdx.x;
  if (tid < kC) {
    int a = tid;
    float s = 0.f, ngt = 0.f;
    for (int c = 0; c < kC; ++c) {
      if (label[b * kC + c] > 0) {
        ngt += 1.f;
        s += sc_buf[b * 400 + c * kC + a];
      }
    }
    if (ngt < 1.f) ngt = 1.f;
    float col = s / ngt;
    if (label[b * kC + a] > 0) col = sc_buf[b * 400 + a * kC + a];
    collect[a] = col;
  }
  __syncthreads();
  if (tid < 2 * kC) z[tid] = (tid < kC) ? score_post[b * kC + tid] : collect[tid - kC];
  __syncthreads();
  if (tid == 0) {
    float mx = z[0];
    for (int i = 1; i < 2 * kC; ++i) mx = fmaxf(mx, z[i]);
    float s = 0.f;
    for (int i = 0; i < 2 * kC; ++i) { z[i] = expf(z[i] - mx); s += z[i]; }
    for (int i = 0; i < 2 * kC; ++i) out[80 + b * 2 * kC + i] = z[i] / s;
  }
}

extern "C" void kernel_launch(void* const* d_in, const int* in_sizes, int n_in,
                              void* d_out, int out_size, void* d_ws, size_t ws_size,
                              hipStream_t stream) {
  (void)in_sizes; (void)n_in; (void)out_size; (void)ws_size;
  const float* x    = (const float*)d_in[0];
  const float* w1   = (const float*)d_in[1];
  const float* b1   = (const float*)d_in[2];
  const float* w2   = (const float*)d_in[3];
  const float* b2   = (const float*)d_in[4];
  const float* wc   = (const float*)d_in[5];
  const float* watt = (const float*)d_in[6];
  const float* batt = (const float*)d_in[7];
  const int*   lbl  = (const int*)d_in[8];
  float* out = (float*)d_out;
  char*  wsb = (char*)d_ws;

  hipFuncSetAttribute(reinterpret_cast<const void*>(&gemm_conv_kernel<750>),
                      hipFuncAttributeMaxDynamicSharedMemorySize, 131072);
  hipFuncSetAttribute(reinterpret_cast<const void*>(&gemm_conv_kernel<3>),
                      hipFuncAttributeMaxDynamicSharedMemorySize, 131072);

  // workspace layout (bytes)
  ushort* Wt1   = (ushort*)(wsb + 0);           // 25,165,824
  ushort* Wt2   = (ushort*)(wsb + 25165824);    // 25,165,824
  ushort* wcb   = (ushort*)(wsb + 50331648);    // 81,920
  ushort* zpage = (ushort*)(wsb + 50413568);    // 4,096
  ushort* xTt   = (ushort*)(wsb + 50417664);    // 6,144,000
  ushort* xJ    = (ushort*)(wsb + 56561664);    // 6,291,456
  ushort* W2b   = (ushort*)(wsb + 62853120);    // 1,572,864
  ushort* Ybuf  = (ushort*)(wsb + 64425984);    // 10,321,920
  float*  scpart= (float*)(wsb + 74747904);     // 10,240
  float*  seq   = (float*)(wsb + 91213824);     // 120,000
  float*  wab   = (float*)(wsb + 91333824);     // 120,000
  float*  scb   = (float*)(wsb + 91453824);     // 3,200
  int*    cnt   = (int*)(wsb + 91457024);       // 64
  int4*   meta  = (int4*)(wsb + 91457088);      // 13,440
  ushort* Ppart = (ushort*)(wsb + 91470848);    // bf16 partials (<= 42 MB)

  const int S_main = 5;   // 240 blocks; ktn 39/38
  const int S_post = 4;   // 320 blocks; ktn 48; partials 42 MB (pinned)

  dim3 blk(256);
  prep_all_kernel<<<dim3(5888), blk, 0, stream>>>(
      w1, w2, wc, x, lbl, Wt1, Wt2, wcb, zpage, xTt, xJ, meta, cnt);
  // main conv1
  gemm_conv_kernel<750><<<dim3(6, 8, S_main), dim3(512), 131072, stream>>>(
      Wt1, xTt, zpage, Ppart, &cnt[2], 1536, 38, 2);
  reduce_kernel<<<dim3(1500), blk, 0, stream>>>(Ppart, b1, Ybuf, &cnt[2], 1536, S_main);
  // main conv2 + fused reduce/seqcas/wa
  gemm_conv_kernel<750><<<dim3(6, 8, S_main), dim3(512), 131072, stream>>>(
      Wt2, Ybuf, zpage, Ppart, &cnt[2], 1536, 38, 2);
  reduce_seqcas_kernel<<<dim3(1500), blk, 0, stream>>>(
      Ppart, b2, wcb, watt, batt, seq, wab, 1536, S_main);
  score_pre_kernel<<<dim3(40), dim3(64), 0, stream>>>(seq, out);  // out[0..39]
  // compact fg+bg aggregation
  ww_build_kernel<<<dim3(6, 16), blk, 0, stream>>>(wab, meta, cnt, W2b);
  ww_gemm_kernel<<<dim3(4, 16, 6), blk, 0, stream>>>(xJ, W2b, cnt, Ybuf);
  // post conv1
  gemm_conv_kernel<3><<<dim3(10, 8, S_post), dim3(512), 131072, stream>>>(
      Wt1, Ybuf, zpage, Ppart, &cnt[1], 2560, 48, 0);
  reduce_kernel<<<dim3(2520), blk, 0, stream>>>(Ppart, b1, Ybuf, &cnt[1], 2560, S_post);
  // post conv2 + fused reduce/classifier
  gemm_conv_kernel<3><<<dim3(10, 8, S_post), dim3(512), 131072, stream>>>(
      Wt2, Ybuf, zpage, Ppart, &cnt[1], 2560, 48, 0);
  reduce_cls_kernel<<<dim3(2520), blk, 0, stream>>>(
      Ppart, b2, wc, meta, cnt, scpart, 2560, S_post);
  cls2_kernel<<<dim3(4), blk, 0, stream>>>(scpart, meta, cnt, out + 40, scb);
  final_kernel<<<dim3(2), dim3(64), 0, stream>>>(out + 40, scb, lbl, out);
}

// Round 19
// 304.400 us; speedup vs baseline: 1.1276x; 1.1276x over previous
//
#include <hip/hip_runtime.h>
#include <math.h>

// ECMNet on gfx950 — FINAL (R17 revert): R13 GEMM core (256x256, 8-wave,
// BK=32, 4-slot ring, counted vmcnt, paired-row swizzle, XCD remap, bf16
// split-K partials) + label-aware bg compaction + fused reduce/seqcas/cls
// + single fused prep kernel. B=2, F=2048, T=750, C=20, topK=93
namespace {
constexpr int kF = 2048;
constexpr int kT = 750;
constexpr int kC = 20;
constexpr int kTop = 93;
}

typedef __bf16 bf16x8 __attribute__((ext_vector_type(8)));
typedef float f32x4 __attribute__((ext_vector_type(4)));

__device__ __forceinline__ ushort f2bf(float f) {
  uint u = __builtin_bit_cast(uint, f);
  uint r = u + 0x7FFFu + ((u >> 16) & 1u);
  return (ushort)(r >> 16);
}
__device__ __forceinline__ float bf2f(ushort u) {
  return __builtin_bit_cast(float, ((uint)u) << 16);
}
__device__ __forceinline__ float leaky(float v) { return v > 0.f ? v : 0.01f * v; }

__device__ __forceinline__ void gload_lds16(const ushort* g, ushort* l) {
  __builtin_amdgcn_global_load_lds(
      (const __attribute__((address_space(1))) void*)g,
      (__attribute__((address_space(3))) void*)l, 16, 0, 0);
}

// ---------------------------------------------------------------------------
// prep_all (R17 proven form): one launch for all preprocessing.
//  blk 0..2047    : w1/w2 rows (2 per block) -> Wt (tap-split bf16)
//  blk 2048..2815 : x transpose -> xTt
//  blk 2816..6911 : xJ build
//  extras: wc convert (blk<160), zpage (blk 0), compact list (blk 1024)
// cnt: [0]=NS, [1]=NS*3, [2]=1500, [4+b]=boff_b, [6+b]=nb_b. meta=(b,c,a,isfg)
// ---------------------------------------------------------------------------
__global__ __launch_bounds__(256) void prep_all_kernel(
    const float* __restrict__ w1, const float* __restrict__ w2,
    const float* __restrict__ wc, const float* __restrict__ x,
    const int* __restrict__ lbl,
    ushort* __restrict__ Wt1, ushort* __restrict__ Wt2,
    ushort* __restrict__ wcb, ushort* __restrict__ zpage,
    ushort* __restrict__ xTt, ushort* __restrict__ xJ,
    int4* __restrict__ meta, int* __restrict__ cnt) {
  __shared__ float smem[6144];   // 24 KB: weight row / transpose tile / xJ buf
  const int blk = blockIdx.x;
  const int tid = threadIdx.x;

  if (blk < 2048) {
    // ---- weight conversion: 2 rows per block ----
    const float* w = (blk < 1024) ? w1 : w2;
    ushort* Wt = (blk < 1024) ? Wt1 : Wt2;
    const int base = (blk & 1023) * 2;
#pragma unroll
    for (int r = 0; r < 2; ++r) {
      const int co = base + r;
      const float4* src = (const float4*)(w + (size_t)co * 6144);
#pragma unroll
      for (int i = 0; i < 6; ++i)
        ((float4*)smem)[tid + i * 256] = src[tid + i * 256];
      __syncthreads();
      float rv[24];
      const float4* lp = (const float4*)smem + tid * 6;
#pragma unroll
      for (int k = 0; k < 6; ++k) {
        float4 f = lp[k];
        rv[k * 4 + 0] = f.x; rv[k * 4 + 1] = f.y;
        rv[k * 4 + 2] = f.z; rv[k * 4 + 3] = f.w;
      }
      const int ci0 = tid * 8;
#pragma unroll
      for (int tap = 0; tap < 3; ++tap) {
        uint4 pk;
        pk.x = (uint)f2bf(rv[0 * 3 + tap]) | ((uint)f2bf(rv[1 * 3 + tap]) << 16);
        pk.y = (uint)f2bf(rv[2 * 3 + tap]) | ((uint)f2bf(rv[3 * 3 + tap]) << 16);
        pk.z = (uint)f2bf(rv[4 * 3 + tap]) | ((uint)f2bf(rv[5 * 3 + tap]) << 16);
        pk.w = (uint)f2bf(rv[6 * 3 + tap]) | ((uint)f2bf(rv[7 * 3 + tap]) << 16);
        *(uint4*)(Wt + (size_t)tap * kF * kF + (size_t)co * kF + ci0) = pk;
      }
      __syncthreads();
    }
    if (blk < 160) {                      // wc: 40960 elems
      int i = blk * 256 + tid;
      wcb[i] = f2bf(wc[i]);
    }
    if (blk == 0) {
      ((float4*)zpage)[tid] = (float4){0.f, 0.f, 0.f, 0.f};
    }
    if (blk == 1024 && tid == 0) {        // compact list
      int n = 0;
      for (int b2 = 0; b2 < 2; ++b2) {
        cnt[4 + b2] = n;
        for (int c = 0; c < kC; ++c) { meta[n] = make_int4(b2, c, c, 1); ++n; }
        for (int c = 0; c < kC; ++c)
          for (int a2 = 0; a2 < kC; ++a2)
            if (lbl[b2 * kC + c] > 0 || c == a2) { meta[n] = make_int4(b2, c, a2, 0); ++n; }
        cnt[6 + b2] = (n - cnt[4 + b2]);
      }
      cnt[0] = n; cnt[1] = n * 3; cnt[2] = 1500; cnt[3] = 0;
    }
  } else if (blk < 2816) {
    // ---- transpose tile: smem as [64][65] ----
    const int loc = blk - 2048;
    const int b = loc / 384, r = loc % 384;
    const int by = r / 12, bx = r % 12;
    const int t0 = bx * 64, f0 = by * 64;
    const int tx = tid & 63, ty4 = tid >> 6;
#pragma unroll
    for (int i = 0; i < 16; ++i) {
      int lf = ty4 + i * 4;
      int t = t0 + tx;
      smem[lf * 65 + tx] = (t < kT) ? x[((size_t)b * kF + f0 + lf) * kT + t] : 0.f;
    }
    __syncthreads();
#pragma unroll
    for (int i = 0; i < 16; ++i) {
      int lt = ty4 + i * 4;
      int t = t0 + lt;
      if (t < kT)
        xTt[(size_t)(b * kT + t) * kF + f0 + tx] = f2bf(smem[tx * 65 + lt]);
    }
  } else {
    // ---- xJ build ----
    const int bid = blk - 2816;           // 0..4095
    const int b = bid >> 11, f = bid & 2047;
    const float* xr = x + ((size_t)b * kF + f) * kT;
    for (int t = tid; t < kT; t += 256) smem[t] = xr[t];
    __syncthreads();
    const int j = tid;
#pragma unroll
    for (int g = 0; g < 3; ++g) {
      float v = (j < 250) ? smem[j * 3 + g] : 0.f;
      xJ[(((size_t)(b * 3 + g) * kF + f) << 8) + j] = f2bf(v);
    }
  }
}

// ---------------------------------------------------------------------------
// W2c[bg][r][j] bf16 from compact meta
// ---------------------------------------------------------------------------
__global__ __launch_bounds__(256) void ww_build_kernel(
    const float* __restrict__ wab, const int4* __restrict__ meta,
    const int* __restrict__ cnt, ushort* __restrict__ W2) {
  const int bg = blockIdx.x;
  const int b = bg / 3, g = bg % 3;
  const int r0 = blockIdx.y * 32;
  const int nb = cnt[6 + b], boff = cnt[4 + b];
  if (r0 >= nb) return;
  __shared__ float ws[kC][256];
  for (int i = threadIdx.x; i < kC * 250; i += 256) {
    int c = i / 250, j = i % 250;
    ws[c][j] = wab[(size_t)(b * kC + c) * kT + j * 3 + g];
  }
  __syncthreads();
  ushort* Wb = W2 + (size_t)bg * 512 * 256;
  const int j = threadIdx.x;
  for (int rr = 0; rr < 32; ++rr) {
    int r = r0 + rr;
    if (r >= nb) break;
    int4 m = meta[boff + r];
    float v = 0.f;
    if (j < 250)
      v = m.w ? ws[m.y][j] : ws[m.z][j] * (1.f - ws[m.y][j]);
    Wb[(size_t)r * 256 + j] = f2bf(v);
  }
}

// ---------------------------------------------------------------------------
// ww GEMM (128x128, 2-phase): FeatY[(boff+s)*3+g][f] = sum_j W2c[s][j]*xJ[f][j]
// ---------------------------------------------------------------------------
__global__ __launch_bounds__(256) void ww_gemm_kernel(
    const ushort* __restrict__ xJ, const ushort* __restrict__ W2,
    const int* __restrict__ cnt, ushort* __restrict__ FeatY) {
  const int bg = blockIdx.z;
  const int b = bg / 3, g = bg % 3;
  const int nb = cnt[6 + b], boff = cnt[4 + b];
  const int s0 = blockIdx.x * 128;
  if (s0 >= nb) return;
  __shared__ ushort sA[2][128 * 64];
  __shared__ ushort sB[2][128 * 64];
  const int tid = threadIdx.x;
  const int w = tid >> 6, lane = tid & 63;
  const int wm = w >> 1, wn = w & 1;
  const int f0 = blockIdx.y * 128;
  const ushort* A = xJ + ((size_t)bg * kF << 8);
  const ushort* Bp = W2 + (size_t)bg * 512 * 256;
  const int srow = lane >> 3;
  const int selem = ((lane & 7) ^ srow) * 8;
  f32x4 acc[4][4];
#pragma unroll
  for (int i = 0; i < 4; ++i)
#pragma unroll
    for (int j = 0; j < 4; ++j) acc[i][j] = (f32x4){0.f, 0.f, 0.f, 0.f};

  auto STAGE = [&](int buf, int kt) {
    const int kin = kt * 64;
#pragma unroll
    for (int i = 0; i < 4; ++i) {
      int r = (w * 4 + i) * 8 + srow;
      gload_lds16(A + (size_t)(f0 + r) * 256 + kin + selem,
                  &sA[buf][(w * 4 + i) * 512]);
    }
#pragma unroll
    for (int i = 0; i < 4; ++i) {
      int r = (w * 4 + i) * 8 + srow;
      gload_lds16(Bp + (size_t)(s0 + r) * 256 + kin + selem,
                  &sB[buf][(w * 4 + i) * 512]);
    }
  };

  STAGE(0, 0);
  asm volatile("s_waitcnt vmcnt(0)" ::: "memory");
  __builtin_amdgcn_s_barrier();

  int cur = 0;
  for (int kt = 0; kt < 4; ++kt) {
    if (kt + 1 < 4) STAGE(cur ^ 1, kt + 1);
#pragma unroll
    for (int ksub = 0; ksub < 2; ++ksub) {
      bf16x8 af[4], bfv[4];
      const int rlow = lane & 7;
#pragma unroll
      for (int fm = 0; fm < 4; ++fm) {
        int row = wm * 64 + fm * 16 + (lane & 15);
        int c16 = (ksub * 4 + (lane >> 4)) ^ rlow;
        af[fm] = *(const bf16x8*)&sA[cur][row * 64 + c16 * 8];
      }
#pragma unroll
      for (int fn = 0; fn < 4; ++fn) {
        int row = wn * 64 + fn * 16 + (lane & 15);
        int c16 = (ksub * 4 + (lane >> 4)) ^ rlow;
        bfv[fn] = *(const bf16x8*)&sB[cur][row * 64 + c16 * 8];
      }
#pragma unroll
      for (int fm = 0; fm < 4; ++fm)
#pragma unroll
        for (int fn = 0; fn < 4; ++fn)
          acc[fm][fn] = __builtin_amdgcn_mfma_f32_16x16x32_bf16(
              af[fm], bfv[fn], acc[fm][fn], 0, 0, 0);
    }
    asm volatile("s_waitcnt vmcnt(0)" ::: "memory");
    __builtin_amdgcn_s_barrier();
    cur ^= 1;
  }

#pragma unroll
  for (int fm = 0; fm < 4; ++fm) {
#pragma unroll
    for (int fn = 0; fn < 4; ++fn) {
      int s = s0 + wn * 64 + fn * 16 + (lane & 15);
      if (s >= nb) continue;
      int row = f0 + wm * 64 + fm * 16 + ((lane >> 4) << 2);
      ushort4 o;
      o.x = f2bf(acc[fm][fn][0]);
      o.y = f2bf(acc[fm][fn][1]);
      o.z = f2bf(acc[fm][fn][2]);
      o.w = f2bf(acc[fm][fn][3]);
      *(ushort4*)&FeatY[(size_t)((boff + s) * 3 + g) * kF + row] = o;
    }
  }
}

// ---------------------------------------------------------------------------
// Direct-conv GEMM (R13 exact): split-K, 256x256, 8 waves, BK=32, 4-slot
// ring, 3-deep prefetch, counted vmcnt(8), pinned 2-phase, paired-row
// swizzle, XCD remap, bf16 partials, device ncols + early exit.
// ---------------------------------------------------------------------------
template <int L>
__global__ __launch_bounds__(512, 1) void gemm_conv_kernel(
    const ushort* __restrict__ A, const ushort* __restrict__ B,
    const ushort* __restrict__ zpage, ushort* __restrict__ Cpart,
    const int* __restrict__ ncp, int NP, int ktn_base, int ktrem) {
  extern __shared__ ushort lds[];
  const int nc = *ncp;
  const int tid = threadIdx.x;
  const int wid = tid >> 6, lane = tid & 63;
  const int wr = wid >> 2, wc = wid & 3;
  const int gx = gridDim.x, gy = gridDim.y;
  const int nwg = gx * gy * gridDim.z;
  const int h = blockIdx.x + gx * (blockIdx.y + gy * blockIdx.z);
  const int lgc = (h & 7) * (nwg >> 3) + (h >> 3);
  const int bx = lgc % gx;
  const int byz = lgc / gx;
  const int co0 = (byz % gy) * 256;
  const int col0 = bx * 256;
  if (col0 >= nc) return;
  const int z = byz / gy;
  const int kt0 = z * ktn_base + (z < ktrem ? z : ktrem);
  const int ktn = ktn_base + (z < ktrem ? 1 : 0);
  const int ktend = kt0 + ktn;

  const int pofs = lane >> 3;
  const int lin_s = (lane & 7) ^ pofs;
  const int mofs = 2 * pofs + (lin_s >> 2);
  const int qseg = (lin_s & 3) * 8;
  const int l15 = lane & 15;
  const int seg8 = ((((l15 & 1) << 2) + (lane >> 4)) ^ (l15 >> 1)) * 8;
  const int off_rl = (l15 >> 1) * 64 + seg8;

  f32x4 acc[8][4];
#pragma unroll
  for (int i = 0; i < 8; ++i)
#pragma unroll
    for (int j = 0; j < 4; ++j) acc[i][j] = (f32x4){0.f, 0.f, 0.f, 0.f};

  auto STAGE_A = [&](int buf, int kt) {
    const int tap = kt >> 6;
    const int kin = (kt & 63) * 32;
    const size_t abase = (size_t)tap * kF * kF + kin + qseg;
#pragma unroll
    for (int l = 0; l < 2; ++l) {
      int m = l * 128 + wid * 16 + mofs;
      gload_lds16(A + abase + (size_t)(co0 + m) * kF,
                  &lds[buf * 16384 + l * 4096 + wid * 512]);
    }
  };
  auto STAGE_B = [&](int buf, int kt) {
    const int tap = kt >> 6;
    const int kin = (kt & 63) * 32;
#pragma unroll
    for (int l = 0; l < 2; ++l) {
      int m = l * 128 + wid * 16 + mofs;
      int col = col0 + m;
      int t = col - (col / L) * L;
      int tt = t + tap - 1;
      const ushort* src = (col < nc && tt >= 0 && tt < L)
          ? B + (size_t)(col + tap - 1) * kF + kin + qseg
          : zpage + qseg;
      gload_lds16(src, &lds[buf * 16384 + 8192 + l * 4096 + wid * 512]);
    }
  };

  STAGE_A(kt0 & 3, kt0);           STAGE_B(kt0 & 3, kt0);
  STAGE_A((kt0 + 1) & 3, kt0 + 1); STAGE_B((kt0 + 1) & 3, kt0 + 1);
  STAGE_A((kt0 + 2) & 3, kt0 + 2); STAGE_B((kt0 + 2) & 3, kt0 + 2);
  asm volatile("s_waitcnt vmcnt(8)" ::: "memory");
  __builtin_amdgcn_s_barrier();
  __builtin_amdgcn_sched_barrier(0);

  for (int kt = kt0; kt < ktend; ++kt) {
    const int buf = kt & 3;
    const int ts = (kt + 3 < ktend) ? kt + 3 : ktend - 1;
    const int bufs = ts & 3;
    const ushort* bb = &lds[buf * 16384];
    bf16x8 bfv[4], af[4];
    STAGE_A(bufs, ts);
#pragma unroll
    for (int fn = 0; fn < 4; ++fn)
      bfv[fn] = *(const bf16x8*)&bb[8192 + wc * 2048 + fn * 512 + off_rl];
#pragma unroll
    for (int fm = 0; fm < 4; ++fm)
      af[fm] = *(const bf16x8*)&bb[wr * 4096 + fm * 512 + off_rl];
    asm volatile("s_waitcnt lgkmcnt(0)" ::: "memory");
    __builtin_amdgcn_sched_barrier(0);
    __builtin_amdgcn_s_setprio(1);
#pragma unroll
    for (int fm = 0; fm < 4; ++fm)
#pragma unroll
      for (int fn = 0; fn < 4; ++fn)
        acc[fm][fn] = __builtin_amdgcn_mfma_f32_16x16x32_bf16(
            af[fm], bfv[fn], acc[fm][fn], 0, 0, 0);
    __builtin_amdgcn_s_setprio(0);
    STAGE_B(bufs, ts);
#pragma unroll
    for (int fm = 0; fm < 4; ++fm)
      af[fm] = *(const bf16x8*)&bb[wr * 4096 + (fm + 4) * 512 + off_rl];
    asm volatile("s_waitcnt lgkmcnt(0)" ::: "memory");
    __builtin_amdgcn_sched_barrier(0);
    __builtin_amdgcn_s_setprio(1);
#pragma unroll
    for (int fm = 0; fm < 4; ++fm)
#pragma unroll
      for (int fn = 0; fn < 4; ++fn)
        acc[fm + 4][fn] = __builtin_amdgcn_mfma_f32_16x16x32_bf16(
            af[fm], bfv[fn], acc[fm + 4][fn], 0, 0, 0);
    __builtin_amdgcn_s_setprio(0);
    asm volatile("s_waitcnt vmcnt(8)" ::: "memory");
    __builtin_amdgcn_s_barrier();
    __builtin_amdgcn_sched_barrier(0);
  }

  ushort* Cz = Cpart + (size_t)z * NP * kF;
#pragma unroll
  for (int fm = 0; fm < 8; ++fm) {
#pragma unroll
    for (int fn = 0; fn < 4; ++fn) {
      int col = col0 + wc * 64 + fn * 16 + l15;
      int row = co0 + wr * 128 + fm * 16 + ((lane >> 4) << 2);
      ushort4 o;
      o.x = f2bf(acc[fm][fn][0]);
      o.y = f2bf(acc[fm][fn][1]);
      o.z = f2bf(acc[fm][fn][2]);
      o.w = f2bf(acc[fm][fn][3]);
      *(ushort4*)&Cz[(size_t)col * kF + row] = o;
    }
  }
}

// ---------------------------------------------------------------------------
// reduce bf16 partials over S + bias + leaky -> bf16 [col][2048]
// ---------------------------------------------------------------------------
__global__ __launch_bounds__(256) void reduce_kernel(
    const ushort* __restrict__ Cpart, const float* __restrict__ bias,
    ushort* __restrict__ Y, const int* __restrict__ ncp, int NP, int S) {
  const int col = blockIdx.x;
  if (col >= *ncp) return;
  const int row0 = threadIdx.x * 8;
  float s[8] = {};
  for (int z = 0; z < S; ++z) {
    const ushort* p = &Cpart[((size_t)z * NP + col) * kF + row0];
    ushort4 a = *(const ushort4*)p;
    ushort4 b = *(const ushort4*)(p + 4);
    s[0] += bf2f(a.x); s[1] += bf2f(a.y); s[2] += bf2f(a.z); s[3] += bf2f(a.w);
    s[4] += bf2f(b.x); s[5] += bf2f(b.y); s[6] += bf2f(b.z); s[7] += bf2f(b.w);
  }
  float4 bv0 = *(const float4*)&bias[row0];
  float4 bv1 = *(const float4*)&bias[row0 + 4];
  ushort4 o0, o1;
  o0.x = f2bf(leaky(s[0] + bv0.x)); o0.y = f2bf(leaky(s[1] + bv0.y));
  o0.z = f2bf(leaky(s[2] + bv0.z)); o0.w = f2bf(leaky(s[3] + bv0.w));
  o1.x = f2bf(leaky(s[4] + bv1.x)); o1.y = f2bf(leaky(s[5] + bv1.y));
  o1.z = f2bf(leaky(s[6] + bv1.z)); o1.w = f2bf(leaky(s[7] + bv1.w));
  *(ushort4*)&Y[(size_t)col * kF + row0] = o0;
  *(ushort4*)&Y[(size_t)col * kF + row0 + 4] = o1;
}

// ---------------------------------------------------------------------------
// fused main-conv2 reduce + seqcas + wa (h2 never materialized)
// ---------------------------------------------------------------------------
__global__ __launch_bounds__(256) void reduce_seqcas_kernel(
    const ushort* __restrict__ Cpart, const float* __restrict__ bias,
    const ushort* __restrict__ wcb, const float* __restrict__ watt,
    const float* __restrict__ batt, float* __restrict__ seq,
    float* __restrict__ wa, int NP, int S) {
  __shared__ float red[4][kC];
  __shared__ float sseq[kC];
  const int col = blockIdx.x;          // b*750+t
  const int tid = threadIdx.x;
  const int wid = tid >> 6, lane = tid & 63;
  const int row0 = tid * 8;
  float s[8] = {};
  for (int z = 0; z < S; ++z) {
    const ushort* p = &Cpart[((size_t)z * NP + col) * kF + row0];
    ushort4 a4 = *(const ushort4*)p;
    ushort4 b4 = *(const ushort4*)(p + 4);
    s[0] += bf2f(a4.x); s[1] += bf2f(a4.y); s[2] += bf2f(a4.z); s[3] += bf2f(a4.w);
    s[4] += bf2f(b4.x); s[5] += bf2f(b4.y); s[6] += bf2f(b4.z); s[7] += bf2f(b4.w);
  }
  float4 bv0 = *(const float4*)&bias[row0];
  float4 bv1 = *(const float4*)&bias[row0 + 4];
  float a[8];
  a[0] = leaky(s[0] + bv0.x); a[1] = leaky(s[1] + bv0.y);
  a[2] = leaky(s[2] + bv0.z); a[3] = leaky(s[3] + bv0.w);
  a[4] = leaky(s[4] + bv1.x); a[5] = leaky(s[5] + bv1.y);
  a[6] = leaky(s[6] + bv1.z); a[7] = leaky(s[7] + bv1.w);
  float p[kC];
#pragma unroll
  for (int c = 0; c < kC; ++c) {
    const ushort* wr = wcb + (size_t)c * kF + row0;
    ushort4 wa4 = *(const ushort4*)wr;
    ushort4 wb4 = *(const ushort4*)(wr + 4);
    p[c] = bf2f(wa4.x) * a[0] + bf2f(wa4.y) * a[1] +
           bf2f(wa4.z) * a[2] + bf2f(wa4.w) * a[3] +
           bf2f(wb4.x) * a[4] + bf2f(wb4.y) * a[5] +
           bf2f(wb4.z) * a[6] + bf2f(wb4.w) * a[7];
  }
#pragma unroll
  for (int off = 32; off; off >>= 1)
#pragma unroll
    for (int c = 0; c < kC; ++c) p[c] += __shfl_xor(p[c], off);
  if (lane == 0)
#pragma unroll
    for (int c = 0; c < kC; ++c) red[wid][c] = p[c];
  __syncthreads();
  if (tid < kC)
    sseq[tid] = red[0][tid] + red[1][tid] + red[2][tid] + red[3][tid];
  __syncthreads();
  if (tid < kC) {
    float z = batt[tid];
#pragma unroll
    for (int a2 = 0; a2 < kC; ++a2) z += watt[tid * kC + a2] * sseq[a2];
    const int b = col / kT, t = col - b * kT;
    seq[(size_t)(b * kC + tid) * kT + t] = sseq[tid];
    wa[(size_t)(b * kC + tid) * kT + t] = 1.f / (1.f + expf(-z));
  }
}

// ---------------------------------------------------------------------------
// fused post-conv2 reduce + classifier dot
// ---------------------------------------------------------------------------
__global__ __launch_bounds__(256) void reduce_cls_kernel(
    const ushort* __restrict__ Cpart, const float* __restrict__ bias,
    const float* __restrict__ wc, const int4* __restrict__ meta,
    const int* __restrict__ cnt, float* __restrict__ scpart, int NP, int S) {
  __shared__ float red[256];
  const int col = blockIdx.x;
  if (col >= cnt[1]) return;
  const int4 m = meta[col / 3];
  const int cls = m.w ? m.y : m.z;
  const int row0 = threadIdx.x * 8;
  float s[8] = {};
  for (int z = 0; z < S; ++z) {
    const ushort* p = &Cpart[((size_t)z * NP + col) * kF + row0];
    ushort4 a = *(const ushort4*)p;
    ushort4 b = *(const ushort4*)(p + 4);
    s[0] += bf2f(a.x); s[1] += bf2f(a.y); s[2] += bf2f(a.z); s[3] += bf2f(a.w);
    s[4] += bf2f(b.x); s[5] += bf2f(b.y); s[6] += bf2f(b.z); s[7] += bf2f(b.w);
  }
  float4 bv0 = *(const float4*)&bias[row0];
  float4 bv1 = *(const float4*)&bias[row0 + 4];
  float4 w0 = *(const float4*)&wc[(size_t)cls * kF + row0];
  float4 w1 = *(const float4*)&wc[(size_t)cls * kF + row0 + 4];
  float acc =
      bf2f(f2bf(leaky(s[0] + bv0.x))) * w0.x + bf2f(f2bf(leaky(s[1] + bv0.y))) * w0.y +
      bf2f(f2bf(leaky(s[2] + bv0.z))) * w0.z + bf2f(f2bf(leaky(s[3] + bv0.w))) * w0.w +
      bf2f(f2bf(leaky(s[4] + bv1.x))) * w1.x + bf2f(f2bf(leaky(s[5] + bv1.y))) * w1.y +
      bf2f(f2bf(leaky(s[6] + bv1.z))) * w1.z + bf2f(f2bf(leaky(s[7] + bv1.w))) * w1.w;
  red[threadIdx.x] = acc;
  __syncthreads();
  for (int t = 128; t > 0; t >>= 1) {
    if (threadIdx.x < t) red[threadIdx.x] += red[threadIdx.x + t];
    __syncthreads();
  }
  if (threadIdx.x == 0) scpart[col] = red[0];
}

// gather per-sample mean over g and scatter (deterministic)
__global__ __launch_bounds__(256) void cls2_kernel(
    const float* __restrict__ scpart, const int4* __restrict__ meta,
    const int* __restrict__ cnt, float* __restrict__ out40,
    float* __restrict__ scb) {
  const int n = blockIdx.x * 256 + threadIdx.x;
  if (n >= cnt[0]) return;
  const int4 m = meta[n];
  float v = (scpart[3 * n] + scpart[3 * n + 1] + scpart[3 * n + 2]) * (1.f / 3.f);
  if (m.w) out40[m.x * kC + m.y] = v;
  else scb[m.x * 400 + m.y * kC + m.z] = v;
}

// top-93 mean over T per (b,c) row — one wave per row, barrier-free
__global__ __launch_bounds__(64) void score_pre_kernel(
    const float* __restrict__ seq, float* __restrict__ out) {
  const int n = blockIdx.x;
  const int lane = threadIdx.x;
  float v[12];
#pragma unroll
  for (int i = 0; i < 12; ++i) {
    int idx = lane + i * 64;
    v[i] = (idx < kT) ? seq[(size_t)n * kT + idx] : -1e30f;
  }
  float sum = 0.f;
  for (int it = 0; it < kTop; ++it) {
    float lm = v[0];
#pragma unroll
    for (int i = 1; i < 12; ++i) lm = fmaxf(lm, v[i]);
    float wm = lm;
#pragma unroll
    for (int off = 32; off; off >>= 1) wm = fmaxf(wm, __shfl_xor(wm, off));
    sum += wm;
    unsigned long long ball = __ballot(lm == wm);
    int first = __ffsll(ball) - 1;
    bool own = (lane == first);
    bool done = false;
#pragma unroll
    for (int i = 0; i < 12; ++i) {
      bool hit = own && !done && (v[i] == wm);
      if (hit) { v[i] = -1e30f; done = true; }
    }
  }
  if (lane == 0) out[n] = sum / (float)kTop;
}

// collect + concat + softmax
__global__ void final_kernel(const float* __restrict__ score_post,
                             const float* __restrict__ sc_buf,
                             const int* __restrict__ label,
                             float* __restrict__ out) {
  __shared__ float z[2 * kC];
  __shared__ float collect[kC];
  const int b = blockIdx.x;
  const int tid = threadIdx.x;
  if (tid < kC) {
    int a = tid;
    float s = 0.f, ngt = 0.f;
    for (int c = 0; c < kC; ++c) {
      if (label[b * kC + c] > 0) {
        ngt += 1.f;
        s += sc_buf[b * 400 + c * kC + a];
      }
    }
    if (ngt < 1.f) ngt = 1.f;
    float col = s / ngt;
    if (label[b * kC + a] > 0) col = sc_buf[b * 400 + a * kC + a];
    collect[a] = col;
  }
  __syncthreads();
  if (tid < 2 * kC) z[tid] = (tid < kC) ? score_post[b * kC + tid] : collect[tid - kC];
  __syncthreads();
  if (tid == 0) {
    float mx = z[0];
    for (int i = 1; i < 2 * kC; ++i) mx = fmaxf(mx, z[i]);
    float s = 0.f;
    for (int i = 0; i < 2 * kC; ++i) { z[i] = expf(z[i] - mx); s += z[i]; }
    for (int i = 0; i < 2 * kC; ++i) out[80 + b * 2 * kC + i] = z[i] / s;
  }
}

extern "C" void kernel_launch(void* const* d_in, const int* in_sizes, int n_in,
                              void* d_out, int out_size, void* d_ws, size_t ws_size,
                              hipStream_t stream) {
  (void)in_sizes; (void)n_in; (void)out_size;
  const float* x    = (const float*)d_in[0];
  const float* w1   = (const float*)d_in[1];
  const float* b1   = (const float*)d_in[2];
  const float* w2   = (const float*)d_in[3];
  const float* b2   = (const float*)d_in[4];
  const float* wc   = (const float*)d_in[5];
  const float* watt = (const float*)d_in[6];
  const float* batt = (const float*)d_in[7];
  const int*   lbl  = (const int*)d_in[8];
  float* out = (float*)d_out;
  char*  wsb = (char*)d_ws;

  hipFuncSetAttribute(reinterpret_cast<const void*>(&gemm_conv_kernel<750>),
                      hipFuncAttributeMaxDynamicSharedMemorySize, 131072);
  hipFuncSetAttribute(reinterpret_cast<const void*>(&gemm_conv_kernel<3>),
                      hipFuncAttributeMaxDynamicSharedMemorySize, 131072);

  // workspace layout (bytes)
  ushort* Wt1   = (ushort*)(wsb + 0);           // 25,165,824
  ushort* Wt2   = (ushort*)(wsb + 25165824);    // 25,165,824
  ushort* wcb   = (ushort*)(wsb + 50331648);    // 81,920
  ushort* zpage = (ushort*)(wsb + 50413568);    // 4,096
  ushort* xTt   = (ushort*)(wsb + 50417664);    // 6,144,000
  ushort* xJ    = (ushort*)(wsb + 56561664);    // 6,291,456
  ushort* W2b   = (ushort*)(wsb + 62853120);    // 1,572,864
  ushort* Ybuf  = (ushort*)(wsb + 64425984);    // 10,321,920
  float*  scpart= (float*)(wsb + 74747904);     // 10,240
  float*  seq   = (float*)(wsb + 91213824);     // 120,000
  float*  wab   = (float*)(wsb + 91333824);     // 120,000
  float*  scb   = (float*)(wsb + 91453824);     // 3,200
  int*    cnt   = (int*)(wsb + 91457024);       // 64
  int4*   meta  = (int4*)(wsb + 91457088);      // 13,440
  ushort* Ppart = (ushort*)(wsb + 91470848);    // bf16 partials

  const int S_main = 5;  // 240 blocks; ktn 39/38
  const size_t ppart_off = 91470848;
  const size_t avail = (ws_size > ppart_off) ? ws_size - ppart_off : 0;
  const int S_post = (avail >= (size_t)8 * 2560 * 2048 * 2) ? 8
                   : (avail >= (size_t)6 * 2560 * 2048 * 2) ? 6 : 4;
  const int ktn_post = 192 / S_post;

  dim3 blk(256);
  prep_all_kernel<<<dim3(6912), blk, 0, stream>>>(
      w1, w2, wc, x, lbl, Wt1, Wt2, wcb, zpage, xTt, xJ, meta, cnt);
  // main conv1
  gemm_conv_kernel<750><<<dim3(6, 8, S_main), dim3(512), 131072, stream>>>(
      Wt1, xTt, zpage, Ppart, &cnt[2], 1536, 38, 2);
  reduce_kernel<<<dim3(1500), blk, 0, stream>>>(Ppart, b1, Ybuf, &cnt[2], 1536, S_main);
  // main conv2 + fused reduce/seqcas/wa
  gemm_conv_kernel<750><<<dim3(6, 8, S_main), dim3(512), 131072, stream>>>(
      Wt2, Ybuf, zpage, Ppart, &cnt[2], 1536, 38, 2);
  reduce_seqcas_kernel<<<dim3(1500), blk, 0, stream>>>(
      Ppart, b2, wcb, watt, batt, seq, wab, 1536, S_main);
  score_pre_kernel<<<dim3(40), dim3(64), 0, stream>>>(seq, out);  // out[0..39]
  // compact fg+bg aggregation
  ww_build_kernel<<<dim3(6, 16), blk, 0, stream>>>(wab, meta, cnt, W2b);
  ww_gemm_kernel<<<dim3(4, 16, 6), blk, 0, stream>>>(xJ, W2b, cnt, Ybuf);
  // post conv1
  gemm_conv_kernel<3><<<dim3(10, 8, S_post), dim3(512), 131072, stream>>>(
      Wt1, Ybuf, zpage, Ppart, &cnt[1], 2560, ktn_post, 0);
  reduce_kernel<<<dim3(2520), blk, 0, stream>>>(Ppart, b1, Ybuf, &cnt[1], 2560, S_post);
  // post conv2 + fused reduce/classifier
  gemm_conv_kernel<3><<<dim3(10, 8, S_post), dim3(512), 131072, stream>>>(
      Wt2, Ybuf, zpage, Ppart, &cnt[1], 2560, ktn_post, 0);
  reduce_cls_kernel<<<dim3(2520), blk, 0, stream>>>(
      Ppart, b2, wc, meta, cnt, scpart, 2560, S_post);
  cls2_kernel<<<dim3(4), blk, 0, stream>>>(scpart, meta, cnt, out + 40, scb);
  final_kernel<<<dim3(2), dim3(64), 0, stream>>>(out + 40, scb, lbl, out);
}